// Round 9
// baseline (286.228 us; speedup 1.0000x reference)
//
#include <hip/hip_runtime.h>
#include <stdint.h>

typedef __attribute__((ext_vector_type(8))) short short8;
typedef __attribute__((ext_vector_type(4))) float f32x4;

// ---- byte offsets into d_ws (total 74,054,656 B; proven ws >= 75.7 MB) ----
#define B_STATS  60416ull      // 4*256 fp32             = 4096
#define B_E2     1178624ull    // 8*8*13*128*32 bf16     = 6815744
#define B_XB     7994368ull    // 2048*3328 bf16         = 13631488
#define B_MAIN   21625856ull   // 16*256*128*25 bf16     = 26214400  (layout = out)
#define B_RES    47840256ull   // 16*256*128*25 bf16     = 26214400  (end 74054656)

#define NTV 51200.0f

__device__ __forceinline__ unsigned short f2bf(float f) {
    unsigned u = __float_as_uint(f);
    return (unsigned short)((u + 0x7fffu + ((u >> 16) & 1u)) >> 16);
}
__device__ __forceinline__ float bf2f(unsigned s) { return __uint_as_float(s << 16); }

__device__ __forceinline__ float wave_sum(float v) {
#pragma unroll
    for (int m = 1; m < 64; m <<= 1) v += __shfl_xor(v, m, 64);
    return v;
}

// async global->LDS, 16B per lane; HW dest = wave-uniform base + lane*16
__device__ __forceinline__ void gl_lds16(const unsigned short* g, unsigned short* l) {
    __builtin_amdgcn_global_load_lds(
        (const __attribute__((address_space(1))) unsigned int*)g,
        (__attribute__((address_space(3))) unsigned int*)l, 16, 0, 0);
}
__device__ __forceinline__ void stage_pair(const unsigned short* g0, const unsigned short* g1,
                                           unsigned short* d) {
    gl_lds16(g0, d);
    gl_lds16(g1, d + 512);
}

// LDS tile swizzle: data (row, quad) stored at short-idx (row^((row>>2)&1))*32 + ((quad^(row&3))<<3)
__device__ __forceinline__ int swz_idx(int row, int quad) {
    int rowX = row ^ ((row >> 2) & 1);
    return rowX * 32 + ((quad ^ (row & 3)) << 3);
}

// K-PREP2X: 3 independent jobs in one launch.
// bids [0,128):   E2 build with inline BnA.
// bids [128,928): residual GEMM, TRANSPOSED (D[oc][m2]) so resp stores are
//                 coalesced 32B runs instead of 64x2B scatter (R8's 16% BW cause).
// bids [928,2976): x -> xb bf16 repack.
__global__ __launch_bounds__(256) void k_prep2x(const int* __restrict__ hop,
                                                const float* __restrict__ emb,
                                                const float* __restrict__ A,
                                                const float* __restrict__ res_w,
                                                const float* __restrict__ w_block,
                                                unsigned short* __restrict__ E2,
                                                const float* __restrict__ x,
                                                unsigned short* __restrict__ xb,
                                                unsigned short* __restrict__ resp,
                                                float* __restrict__ stats) {
    __shared__ __align__(16) char smem[16384];
    int bid = blockIdx.x, tid = threadIdx.x;

    if (bid < 128) {
        // ---- E2 build (inline BnA) ----
        float* bl = (float*)smem;            // 3*625 = 7500 B
        float* wl = (float*)smem + 1875;     // 3*64  =  768 B
        int half = bid & 1, og = (bid >> 1) & 7, h = bid >> 4;

        if (tid < 75) {                      // k3 = tid/25, w = tid%25
            int k3 = tid / 25, w = tid - k3*25;
            int g = k3*8 + h;
            float nb = 0.f, na = 0.f;
            for (int v = 0; v < 25; v++) {
                float e = emb[g*12 + hop[v*25 + w]];
                nb += e*e;
                float a = A[((size_t)g*25 + v)*25 + w];
                na += a*a;
            }
            nb = sqrtf(nb) + 1e-4f;
            na = sqrtf(na) + 1e-4f;
            for (int v = 0; v < 25; v++) {
                float e = emb[g*12 + hop[v*25 + w]];
                float a = A[((size_t)g*25 + v)*25 + w];
                bl[k3*625 + v*25 + w] = e/nb + a/na;
            }
        }
        if (tid < 192) {
            int k3 = tid >> 6, o = (tid >> 4) & 3, c = tid & 15;
            wl[tid] = w_block[(k3*256 + h*32 + og*4 + o)*16 + c];
        }
        __syncthreads();

        unsigned short* dst = E2 + (size_t)(h*8 + og)*53248;
        int e0 = half * 26624;
        for (int e = e0 + tid; e < e0 + 26624; e += 256) {
            int kc = e >> 12;
            int n  = (e >> 5) & 127;
            int kk = e & 31;
            int k  = kc*32 + kk;
            int o  = n >> 5, w = n & 31;
            float val = 0.f;
            if (k < 400 && w < 25) {
                int c = k / 25, v = k - c*25;
                val = wl[0*64 + o*16 + c] * bl[0*625 + v*25 + w]
                    + wl[1*64 + o*16 + c] * bl[1*625 + v*25 + w]
                    + wl[2*64 + o*16 + c] * bl[2*625 + v*25 + w];
            }
            dst[e] = f2bf(val);
        }
    } else if (bid < 928) {
        // ---- residual GEMM (transposed): D[oc][m2] = res_w[oc][c] . x^T[c][m2] ----
        // pair (mt, nt=0/1) at bids b2, b2+400 -> same XCD (128%8==400%8==0)
        unsigned short* lds = (unsigned short*)smem;   // [X 4096][W 4096] shorts
        int b2 = bid - 128;
        int nt = (b2 >= 400) ? 1 : 0;
        int mt = b2 - nt*400;

        int lane = tid & 63, wave = tid >> 6;
        int wo = wave >> 1, wm2 = wave & 1;       // wo -> oc half, wm2 -> m2 half
        int lane15 = lane & 15, quad = lane >> 4;

        int n  = mt / 25;
        int off = (mt - n*25) * 128;
        const float* xb2 = x + (size_t)n*409600 + off;
        const float* rw  = res_w + (size_t)nt*128*128;   // [128 oc rows][128 c]

        int c2 = tid >> 4, seg = tid & 15;   // c-pair (2c2,2c2+1), row = seg + 16j
        int wbase = 2*(c2 & 3), qn = c2 >> 2;

        f32x4 acc[4][4] = {};                // [oc-tile i][m2-tile j]

        for (int kc = 0; kc < 4; kc++) {
            const float* xc0 = xb2 + (size_t)(kc*32 + 2*c2)*3200;
            const float* xc1 = xc0 + 3200;
            const float2* rp2 = (const float2*)(rw + kc*32 + 2*c2);  // row stride 64 float2
#pragma unroll
            for (int j = 0; j < 8; j++) {
                int m = seg + 16*j;
                unsigned pkA = (unsigned)f2bf(xc0[m]) | ((unsigned)f2bf(xc1[m]) << 16);
                *(unsigned*)&lds[swz_idx(m, qn) + wbase] = pkA;          // X tile [m2][c]
                float2 rv = rp2[m*64];
                unsigned pkB = (unsigned)f2bf(rv.x) | ((unsigned)f2bf(rv.y) << 16);
                *(unsigned*)&lds[4096 + swz_idx(m, qn) + wbase] = pkB;   // W tile [oc][c]
            }
            __syncthreads();

            short8 af[4], bq[4];
#pragma unroll
            for (int i = 0; i < 4; i++) {
                af[i] = *(const short8*)&lds[4096 + swz_idx(wo*64 + i*16 + lane15, quad)];  // A = W
                bq[i] = *(const short8*)&lds[swz_idx(wm2*64 + i*16 + lane15, quad)];        // B = X
            }
#pragma unroll
            for (int i = 0; i < 4; i++)
#pragma unroll
                for (int j = 0; j < 4; j++)
                    acc[i][j] = __builtin_amdgcn_mfma_f32_16x16x32_bf16(af[i], bq[j], acc[i][j], 0, 0, 0);
            __syncthreads();
        }

        // epilogue: oc = nt*128 + wo*64 + i*16 + quad*4 + r (uniform per lane-quad),
        // m2loc = (mt%25)*128 + wm2*64 + j*16 + lane15 (consecutive across lane15 ->
        // 32B runs per quad-group). resp base for this n:
        size_t robase = (size_t)n*819200 + (size_t)off + wm2*64 + lane15;
        unsigned short* rb = resp + robase;
#pragma unroll
        for (int i = 0; i < 4; i++) {
#pragma unroll
            for (int r = 0; r < 4; r++) {
                int oc = nt*128 + wo*64 + i*16 + quad*4 + r;
                float s1 = 0.f, s2 = 0.f;
#pragma unroll
                for (int j = 0; j < 4; j++) {
                    float val = acc[i][j][r];
                    rb[(size_t)oc*3200 + j*16] = f2bf(val);
                    s1 += val;
                    s2 = fmaf(val, val, s2);
                }
                // reduce across lane15 (same quad -> same oc)
                s1 += __shfl_xor(s1, 1, 64); s1 += __shfl_xor(s1, 2, 64);
                s1 += __shfl_xor(s1, 4, 64); s1 += __shfl_xor(s1, 8, 64);
                s2 += __shfl_xor(s2, 1, 64); s2 += __shfl_xor(s2, 2, 64);
                s2 += __shfl_xor(s2, 4, 64); s2 += __shfl_xor(s2, 8, 64);
                if (lane15 == 0) {
                    atomicAdd(&stats[512 + oc], s1);
                    atomicAdd(&stats[768 + oc], s2);
                }
            }
        }
    } else {
        // ---- x -> xb bf16 repack ----
        int b = bid - 928;
        int n_ = b >> 7, t_ = b & 127;
        unsigned short* row = xb + (size_t)b * 3328;
        for (int idx = tid; idx < 3200; idx += 256) {
            int c = idx / 25, v = idx - c*25;
            float val = x[(((size_t)n_*128 + c)*128 + t_)*25 + v];
            row[(c >> 4)*416 + (c & 15)*25 + v] = f2bf(val);
        }
        if (tid < 128) row[(tid >> 4)*416 + 400 + (tid & 15)] = 0;
    }
}

// K-GC: pure main GEMM, 1024 blocks, R2-exact loop. 2x16KB dbuf,
// stage-next-before-compute, ONE syncthreads per iter. XCD-pinned h=bid&7.
// Output layout [n][oc][t][v] (= out).
__global__ __launch_bounds__(256) void k_gc(const unsigned short* __restrict__ xb,
                                            const unsigned short* __restrict__ E2,
                                            unsigned short* __restrict__ mainp,
                                            float* __restrict__ stats) {
    __shared__ unsigned short lds[16384];
    int bid = blockIdx.x, tid = threadIdx.x;
    int lane = tid & 63, wave = tid >> 6;
    int wm = wave >> 1, wn = wave & 1;
    int lane15 = lane & 15, quad = lane >> 4;

    // inverse swizzle for linear gl_lds destinations (loop-invariant)
    int Lrow0 = wave*32 + (lane >> 2), Lq = lane & 3;
    int r0 = Lrow0 ^ ((Lrow0 >> 2) & 1), q0 = Lq ^ (r0 & 3);
    int Lrow1 = Lrow0 + 16;
    int r1 = Lrow1 ^ ((Lrow1 >> 2) & 1), q1 = Lq ^ (r1 & 3);
    const int adoff = wave*1024 + lane*8;

    int h = bid & 7, og = (bid >> 3) & 7, mt = bid >> 6;

    const unsigned short* agA0 = xb + (size_t)(mt*128 + r0)*3328 + h*416 + q0*8;
    const unsigned short* agA1 = xb + (size_t)(mt*128 + r1)*3328 + h*416 + q1*8;
    const unsigned short* eb   = E2 + (size_t)(h*8 + og)*53248;
    const unsigned short* bgB0 = eb + r0*32 + q0*8;
    const unsigned short* bgB1 = eb + r1*32 + q1*8;

    f32x4 acc[4][4] = {};

    // prologue: stage kc=0 into buf0
    stage_pair(agA0, agA1, lds + adoff);
    stage_pair(bgB0, bgB1, lds + 4096 + adoff);
    __syncthreads();

    for (int kc = 0; kc < 13; kc++) {
        int cur = (kc & 1) << 13;            // 0 or 8192
        if (kc < 12) {
            int nxt = 8192 - cur;
            stage_pair(agA0 + (kc+1)*32,           agA1 + (kc+1)*32,           lds + nxt + adoff);
            stage_pair(bgB0 + (size_t)(kc+1)*4096, bgB1 + (size_t)(kc+1)*4096, lds + nxt + 4096 + adoff);
            __builtin_amdgcn_sched_barrier(0);   // keep stage issue ahead of compute
        }
        const unsigned short* Ac = lds + cur;
        const unsigned short* Bc = lds + cur + 4096;

        short8 af[4], bq[4];
#pragma unroll
        for (int i = 0; i < 4; i++) {
            af[i] = *(const short8*)&Ac[swz_idx(wm*64 + i*16 + lane15, quad)];
            bq[i] = *(const short8*)&Bc[swz_idx(wn*64 + i*16 + lane15, quad)];
        }
#pragma unroll
        for (int i = 0; i < 4; i++)
#pragma unroll
            for (int j = 0; j < 4; j++)
                acc[i][j] = __builtin_amdgcn_mfma_f32_16x16x32_bf16(af[i], bq[j], acc[i][j], 0, 0, 0);
        if (kc < 12) __syncthreads();        // drains this iter's stage (post-MFMA: cheap)
    }

    // epilogue: n = wn*64 + j*16 + lane15 = o*32 + w; mainp layout [n][oc][t][w]
    float s1[2] = {0.f, 0.f}, s2[2] = {0.f, 0.f};
#pragma unroll
    for (int j = 0; j < 4; j++) {
        int w = (j & 1)*16 + lane15;
        int p = j >> 1;
        if (w < 25) {
            int oc = h*32 + og*4 + wn*2 + p;
#pragma unroll
            for (int i = 0; i < 4; i++) {
                int tb = wm*64 + i*16 + quad*4;
#pragma unroll
                for (int r = 0; r < 4; r++) {
                    float val = acc[i][j][r];
                    mainp[((size_t)(mt*256 + oc)*128 + tb + r)*25 + w] = f2bf(val);
                    s1[p] += val;
                    s2[p] = fmaf(val, val, s2[p]);
                }
            }
        }
    }
#pragma unroll
    for (int p = 0; p < 2; p++) {
        float a = wave_sum(s1[p]);
        float b = wave_sum(s2[p]);
        if (lane == 0) {
            int oc = h*32 + og*4 + wn*2 + p;
            atomicAdd(&stats[oc], a);
            atomicAdd(&stats[256 + oc], b);
        }
    }
}

// K-FINAL: out = relu(BN1(main) + BN2(res)); mainp/resp layout == out layout ->
// pure coalesced affine elementwise. 1600 blocks x 256 thr x 4 chunks x 8 elems.
__global__ __launch_bounds__(256) void k_final(const float* __restrict__ bn_g,
                                               const float* __restrict__ bn_b,
                                               const float* __restrict__ rbn_g,
                                               const float* __restrict__ rbn_b,
                                               const float* __restrict__ stats,
                                               const unsigned short* __restrict__ mainp,
                                               const unsigned short* __restrict__ resp,
                                               float* __restrict__ out) {
    __shared__ float4 cf[8];
    int bid = blockIdx.x, tid = threadIdx.x;
    int base_row = (bid * 1024) / 400;
    if (tid < 8) {
        int row = base_row + tid;
        if (row < 4096) {
            int oc = row & 255;
            const float inv = 1.f / NTV;
            float s1 = stats[oc],       s2 = stats[256 + oc];
            float r1v = stats[512 + oc], r2v = stats[768 + oc];
            float mm = s1*inv, vm = s2*inv - mm*mm;
            float mr = r1v*inv, vr = r2v*inv - mr*mr;
            float a1 = bn_g[oc]  * rsqrtf(vm + 1e-5f);
            float c1 = bn_b[oc]  - a1*mm;
            float a2 = rbn_g[oc] * rsqrtf(vr + 1e-5f);
            float c2 = rbn_b[oc] - a2*mr;
            cf[tid] = make_float4(a1, c1, a2, c2);
        }
    }
    __syncthreads();

    const uint4* m4 = (const uint4*)mainp;
    const uint4* r4 = (const uint4*)resp;
    float4* o4 = (float4*)out;
#pragma unroll
    for (int r = 0; r < 4; r++) {
        int chunk = bid*1024 + r*256 + tid;
        uint4 mu = m4[chunk];
        uint4 ru = r4[chunk];
        float4 C = cf[chunk/400 - base_row];
        float4 f0, f1;
        f0.x = fmaxf(fmaf(C.x, __uint_as_float(mu.x << 16),        C.y)
                   + fmaf(C.z, __uint_as_float(ru.x << 16),        C.w), 0.f);
        f0.y = fmaxf(fmaf(C.x, __uint_as_float(mu.x & 0xffff0000u), C.y)
                   + fmaf(C.z, __uint_as_float(ru.x & 0xffff0000u), C.w), 0.f);
        f0.z = fmaxf(fmaf(C.x, __uint_as_float(mu.y << 16),        C.y)
                   + fmaf(C.z, __uint_as_float(ru.y << 16),        C.w), 0.f);
        f0.w = fmaxf(fmaf(C.x, __uint_as_float(mu.y & 0xffff0000u), C.y)
                   + fmaf(C.z, __uint_as_float(ru.y & 0xffff0000u), C.w), 0.f);
        f1.x = fmaxf(fmaf(C.x, __uint_as_float(mu.z << 16),        C.y)
                   + fmaf(C.z, __uint_as_float(ru.z << 16),        C.w), 0.f);
        f1.y = fmaxf(fmaf(C.x, __uint_as_float(mu.z & 0xffff0000u), C.y)
                   + fmaf(C.z, __uint_as_float(ru.z & 0xffff0000u), C.w), 0.f);
        f1.z = fmaxf(fmaf(C.x, __uint_as_float(mu.w << 16),        C.y)
                   + fmaf(C.z, __uint_as_float(ru.w << 16),        C.w), 0.f);
        f1.w = fmaxf(fmaf(C.x, __uint_as_float(mu.w & 0xffff0000u), C.y)
                   + fmaf(C.z, __uint_as_float(ru.w & 0xffff0000u), C.w), 0.f);
        o4[chunk*2]     = f0;
        o4[chunk*2 + 1] = f1;
    }
}

extern "C" void kernel_launch(void* const* d_in, const int* in_sizes, int n_in,
                              void* d_out, int out_size, void* d_ws, size_t ws_size,
                              hipStream_t stream) {
    const float* x        = (const float*)d_in[0];
    const int*   hop      = (const int*)  d_in[1];
    const float* emb      = (const float*)d_in[2];
    const float* A        = (const float*)d_in[3];
    const float* w_block  = (const float*)d_in[4];
    // d_in[5] b_block, d_in[9] res_b: per-channel biases cancel under batchnorm.
    const float* bn_g     = (const float*)d_in[6];
    const float* bn_b     = (const float*)d_in[7];
    const float* res_w    = (const float*)d_in[8];
    const float* rbn_g    = (const float*)d_in[10];
    const float* rbn_b    = (const float*)d_in[11];
    float* out = (float*)d_out;

    char* ws = (char*)d_ws;
    float*          stats  = (float*)(ws + B_STATS);
    unsigned short* E2     = (unsigned short*)(ws + B_E2);
    unsigned short* xb     = (unsigned short*)(ws + B_XB);
    unsigned short* mainp  = (unsigned short*)(ws + B_MAIN);
    unsigned short* resp   = (unsigned short*)(ws + B_RES);

    hipMemsetAsync(stats, 0, 4096, stream);   // capture-safe (harness reset uses it)
    k_prep2x <<<2976, 256, 0, stream>>>(hop, emb, A, res_w, w_block, E2, x, xb, resp, stats);
    k_gc     <<<1024, 256, 0, stream>>>(xb, E2, mainp, stats);
    k_final  <<<1600, 256, 0, stream>>>(bn_g, bn_b, rbn_g, rbn_b, stats, mainp, resp, out);
}

// Round 10
// 206.470 us; speedup vs baseline: 1.3863x; 1.3863x over previous
//
#include <hip/hip_runtime.h>
#include <stdint.h>

typedef __attribute__((ext_vector_type(8))) short short8;
typedef __attribute__((ext_vector_type(4))) float f32x4;

// ---- byte offsets into d_ws (total 74,054,656 B; proven ws >= 75.7 MB) ----
#define B_STATS  60416ull      // 4*256 fp32             = 4096
#define B_E2     1178624ull    // 8*8*13*128*32 bf16     = 6815744
#define B_XB     7994368ull    // 2048*3328 bf16         = 13631488
#define B_MAIN   21625856ull   // 16*256*128*25 bf16     = 26214400  (layout = out)
#define B_RES    47840256ull   // 16*256*128*25 bf16     = 26214400  (end 74054656)

#define NTV 51200.0f

__device__ __forceinline__ unsigned short f2bf(float f) {
    unsigned u = __float_as_uint(f);
    return (unsigned short)((u + 0x7fffu + ((u >> 16) & 1u)) >> 16);
}
__device__ __forceinline__ float bf2f(unsigned s) { return __uint_as_float(s << 16); }

__device__ __forceinline__ float wave_sum(float v) {
#pragma unroll
    for (int m = 1; m < 64; m <<= 1) v += __shfl_xor(v, m, 64);
    return v;
}

// async global->LDS, 16B per lane; HW dest = wave-uniform base + lane*16
__device__ __forceinline__ void gl_lds16(const unsigned short* g, unsigned short* l) {
    __builtin_amdgcn_global_load_lds(
        (const __attribute__((address_space(1))) unsigned int*)g,
        (__attribute__((address_space(3))) unsigned int*)l, 16, 0, 0);
}
__device__ __forceinline__ void stage_pair(const unsigned short* g0, const unsigned short* g1,
                                           unsigned short* d) {
    gl_lds16(g0, d);
    gl_lds16(g1, d + 512);
}

// LDS tile swizzle: data (row, quad) stored at short-idx (row^((row>>2)&1))*32 + ((quad^(row&3))<<3)
__device__ __forceinline__ int swz_idx(int row, int quad) {
    int rowX = row ^ ((row >> 2) & 1);
    return rowX * 32 + ((quad ^ (row & 3)) << 3);
}

// K-PREP2X: 3 independent jobs in one launch.
// bids [0,128):   E2 build with inline BnA.
// bids [128,928): residual GEMM (R8-exact; R9's transposed epilogue reverted —
//                 its shfl chains doubled the kernel, scatter was NOT the limiter).
// bids [928,2976): x -> xb repack, block = (n,c): CONTIGUOUS 12.8KB read (no
//                 gather), scatter moved to fire-and-forget write side.
__global__ __launch_bounds__(256) void k_prep2x(const int* __restrict__ hop,
                                                const float* __restrict__ emb,
                                                const float* __restrict__ A,
                                                const float* __restrict__ res_w,
                                                const float* __restrict__ w_block,
                                                unsigned short* __restrict__ E2,
                                                const float* __restrict__ x,
                                                unsigned short* __restrict__ xb,
                                                unsigned short* __restrict__ resp,
                                                float* __restrict__ stats) {
    __shared__ __align__(16) char smem[16384];
    int bid = blockIdx.x, tid = threadIdx.x;

    if (bid < 128) {
        // ---- E2 build (inline BnA) ----
        float* bl = (float*)smem;            // 3*625 = 7500 B
        float* wl = (float*)smem + 1875;     // 3*64  =  768 B
        int half = bid & 1, og = (bid >> 1) & 7, h = bid >> 4;

        if (tid < 75) {                      // k3 = tid/25, w = tid%25
            int k3 = tid / 25, w = tid - k3*25;
            int g = k3*8 + h;
            float nb = 0.f, na = 0.f;
            for (int v = 0; v < 25; v++) {
                float e = emb[g*12 + hop[v*25 + w]];
                nb += e*e;
                float a = A[((size_t)g*25 + v)*25 + w];
                na += a*a;
            }
            nb = sqrtf(nb) + 1e-4f;
            na = sqrtf(na) + 1e-4f;
            for (int v = 0; v < 25; v++) {
                float e = emb[g*12 + hop[v*25 + w]];
                float a = A[((size_t)g*25 + v)*25 + w];
                bl[k3*625 + v*25 + w] = e/nb + a/na;
            }
        }
        if (tid < 192) {
            int k3 = tid >> 6, o = (tid >> 4) & 3, c = tid & 15;
            wl[tid] = w_block[(k3*256 + h*32 + og*4 + o)*16 + c];
        }
        __syncthreads();

        unsigned short* dst = E2 + (size_t)(h*8 + og)*53248;
        int e0 = half * 26624;
        for (int e = e0 + tid; e < e0 + 26624; e += 256) {
            int kc = e >> 12;
            int n  = (e >> 5) & 127;
            int kk = e & 31;
            int k  = kc*32 + kk;
            int o  = n >> 5, w = n & 31;
            float val = 0.f;
            if (k < 400 && w < 25) {
                int c = k / 25, v = k - c*25;
                val = wl[0*64 + o*16 + c] * bl[0*625 + v*25 + w]
                    + wl[1*64 + o*16 + c] * bl[1*625 + v*25 + w]
                    + wl[2*64 + o*16 + c] * bl[2*625 + v*25 + w];
            }
            dst[e] = f2bf(val);
        }
    } else if (bid < 928) {
        // ---- residual GEMM (R8-exact): M=(b,v)=51200 x K=128 x N=256 ----
        // pair (mt, nt=0/1) at bids b2, b2+400 -> same XCD (128%8==400%8==0)
        unsigned short* lds = (unsigned short*)smem;   // [A 4096][B 4096] shorts
        int b2 = bid - 128;
        int nt = (b2 >= 400) ? 1 : 0;
        int mt = b2 - nt*400;

        int lane = tid & 63, wave = tid >> 6;
        int wm = wave >> 1, wn = wave & 1;
        int lane15 = lane & 15, quad = lane >> 4;

        int n  = mt / 25;
        int off = (mt - n*25) * 128;
        const float* xb2 = x + (size_t)n*409600 + off;
        const float* rw  = res_w + (size_t)nt*128*128;   // [128 rows][128 cols]

        int c2 = tid >> 4, seg = tid & 15;   // c-pair (2c2,2c2+1), m = seg + 16j
        int wbase = 2*(c2 & 3), qn = c2 >> 2;

        f32x4 acc[4][4] = {};

        for (int kc = 0; kc < 4; kc++) {
            const float* xc0 = xb2 + (size_t)(kc*32 + 2*c2)*3200;
            const float* xc1 = xc0 + 3200;
            const float2* rp2 = (const float2*)(rw + kc*32 + 2*c2);  // row stride 64 float2
#pragma unroll
            for (int j = 0; j < 8; j++) {
                int m = seg + 16*j;
                unsigned pkA = (unsigned)f2bf(xc0[m]) | ((unsigned)f2bf(xc1[m]) << 16);
                *(unsigned*)&lds[swz_idx(m, qn) + wbase] = pkA;
                float2 rv = rp2[m*64];
                unsigned pkB = (unsigned)f2bf(rv.x) | ((unsigned)f2bf(rv.y) << 16);
                *(unsigned*)&lds[4096 + swz_idx(m, qn) + wbase] = pkB;
            }
            __syncthreads();

            short8 af[4], bq[4];
#pragma unroll
            for (int i = 0; i < 4; i++) {
                af[i] = *(const short8*)&lds[swz_idx(wm*64 + i*16 + lane15, quad)];
                bq[i] = *(const short8*)&lds[4096 + swz_idx(wn*64 + i*16 + lane15, quad)];
            }
#pragma unroll
            for (int i = 0; i < 4; i++)
#pragma unroll
                for (int j = 0; j < 4; j++)
                    acc[i][j] = __builtin_amdgcn_mfma_f32_16x16x32_bf16(af[i], bq[j], acc[i][j], 0, 0, 0);
            __syncthreads();
        }

#pragma unroll
        for (int j = 0; j < 4; j++) {
            int oc = nt*128 + wn*64 + j*16 + lane15;
            float s1 = 0.f, s2 = 0.f;
#pragma unroll
            for (int i = 0; i < 4; i++) {
                int m2b = mt*128 + wm*64 + i*16 + quad*4;
#pragma unroll
                for (int r = 0; r < 4; r++) {
                    float val = acc[i][j][r];
                    int m2e = m2b + r;
                    int b = m2e / 25, v = m2e - b*25;
                    int nn = b >> 7, t = b & 127;
                    resp[((size_t)(nn*256 + oc)*128 + t)*25 + v] = f2bf(val);
                    s1 += val;
                    s2 = fmaf(val, val, s2);
                }
            }
            s1 += __shfl_xor(s1, 16, 64); s1 += __shfl_xor(s1, 32, 64);
            s2 += __shfl_xor(s2, 16, 64); s2 += __shfl_xor(s2, 32, 64);
            if (quad == 0) {
                atomicAdd(&stats[512 + oc], s1);
                atomicAdd(&stats[768 + oc], s2);
            }
        }
    } else {
        // ---- x -> xb repack, block = (n,c) ----
        // Read: one contiguous 3200-float slab (perfect coalescing, no gather).
        // Write: 50B runs at 6656B stride (fire-and-forget scatter).
        int b = bid - 928;                   // b = n*128 + c
        int n_ = b >> 7, c = b & 127;
        const float* src = x + (size_t)b * 3200;
        unsigned short* dstBase = xb + (size_t)n_*128*3328 + (c >> 4)*416 + (c & 15)*25;
        for (int idx = tid; idx < 3200; idx += 256) {
            int t = idx / 25, v = idx - t*25;
            dstBase[(size_t)t*3328 + v] = f2bf(src[idx]);
        }
        if (c < 8) {                         // zero pads kb=c for all t of this n
            unsigned short* p = xb + (size_t)n_*128*3328 + c*416 + 400;
            int t = tid >> 1, j = (tid & 1) * 8;
            *(uint4*)&p[(size_t)t*3328 + j] = make_uint4(0, 0, 0, 0);
        }
    }
}

// K-GC: pure main GEMM, 1024 blocks, R2-exact loop. 2x16KB dbuf,
// stage-next-before-compute, ONE syncthreads per iter. XCD-pinned h=bid&7.
// Output layout [n][oc][t][v] (= out).
__global__ __launch_bounds__(256) void k_gc(const unsigned short* __restrict__ xb,
                                            const unsigned short* __restrict__ E2,
                                            unsigned short* __restrict__ mainp,
                                            float* __restrict__ stats) {
    __shared__ unsigned short lds[16384];
    int bid = blockIdx.x, tid = threadIdx.x;
    int lane = tid & 63, wave = tid >> 6;
    int wm = wave >> 1, wn = wave & 1;
    int lane15 = lane & 15, quad = lane >> 4;

    // inverse swizzle for linear gl_lds destinations (loop-invariant)
    int Lrow0 = wave*32 + (lane >> 2), Lq = lane & 3;
    int r0 = Lrow0 ^ ((Lrow0 >> 2) & 1), q0 = Lq ^ (r0 & 3);
    int Lrow1 = Lrow0 + 16;
    int r1 = Lrow1 ^ ((Lrow1 >> 2) & 1), q1 = Lq ^ (r1 & 3);
    const int adoff = wave*1024 + lane*8;

    int h = bid & 7, og = (bid >> 3) & 7, mt = bid >> 6;

    const unsigned short* agA0 = xb + (size_t)(mt*128 + r0)*3328 + h*416 + q0*8;
    const unsigned short* agA1 = xb + (size_t)(mt*128 + r1)*3328 + h*416 + q1*8;
    const unsigned short* eb   = E2 + (size_t)(h*8 + og)*53248;
    const unsigned short* bgB0 = eb + r0*32 + q0*8;
    const unsigned short* bgB1 = eb + r1*32 + q1*8;

    f32x4 acc[4][4] = {};

    // prologue: stage kc=0 into buf0
    stage_pair(agA0, agA1, lds + adoff);
    stage_pair(bgB0, bgB1, lds + 4096 + adoff);
    __syncthreads();

    for (int kc = 0; kc < 13; kc++) {
        int cur = (kc & 1) << 13;            // 0 or 8192
        if (kc < 12) {
            int nxt = 8192 - cur;
            stage_pair(agA0 + (kc+1)*32,           agA1 + (kc+1)*32,           lds + nxt + adoff);
            stage_pair(bgB0 + (size_t)(kc+1)*4096, bgB1 + (size_t)(kc+1)*4096, lds + nxt + 4096 + adoff);
            __builtin_amdgcn_sched_barrier(0);   // keep stage issue ahead of compute
        }
        const unsigned short* Ac = lds + cur;
        const unsigned short* Bc = lds + cur + 4096;

        short8 af[4], bq[4];
#pragma unroll
        for (int i = 0; i < 4; i++) {
            af[i] = *(const short8*)&Ac[swz_idx(wm*64 + i*16 + lane15, quad)];
            bq[i] = *(const short8*)&Bc[swz_idx(wn*64 + i*16 + lane15, quad)];
        }
#pragma unroll
        for (int i = 0; i < 4; i++)
#pragma unroll
            for (int j = 0; j < 4; j++)
                acc[i][j] = __builtin_amdgcn_mfma_f32_16x16x32_bf16(af[i], bq[j], acc[i][j], 0, 0, 0);
        if (kc < 12) __syncthreads();        // drains this iter's stage (post-MFMA: cheap)
    }

    // epilogue: n = wn*64 + j*16 + lane15 = o*32 + w; mainp layout [n][oc][t][w]
    float s1[2] = {0.f, 0.f}, s2[2] = {0.f, 0.f};
#pragma unroll
    for (int j = 0; j < 4; j++) {
        int w = (j & 1)*16 + lane15;
        int p = j >> 1;
        if (w < 25) {
            int oc = h*32 + og*4 + wn*2 + p;
#pragma unroll
            for (int i = 0; i < 4; i++) {
                int tb = wm*64 + i*16 + quad*4;
#pragma unroll
                for (int r = 0; r < 4; r++) {
                    float val = acc[i][j][r];
                    mainp[((size_t)(mt*256 + oc)*128 + tb + r)*25 + w] = f2bf(val);
                    s1[p] += val;
                    s2[p] = fmaf(val, val, s2[p]);
                }
            }
        }
    }
#pragma unroll
    for (int p = 0; p < 2; p++) {
        float a = wave_sum(s1[p]);
        float b = wave_sum(s2[p]);
        if (lane == 0) {
            int oc = h*32 + og*4 + wn*2 + p;
            atomicAdd(&stats[oc], a);
            atomicAdd(&stats[256 + oc], b);
        }
    }
}

// K-FINAL: out = relu(BN1(main) + BN2(res)); mainp/resp layout == out layout ->
// pure coalesced affine elementwise. 1600 blocks x 256 thr x 4 chunks x 8 elems.
__global__ __launch_bounds__(256) void k_final(const float* __restrict__ bn_g,
                                               const float* __restrict__ bn_b,
                                               const float* __restrict__ rbn_g,
                                               const float* __restrict__ rbn_b,
                                               const float* __restrict__ stats,
                                               const unsigned short* __restrict__ mainp,
                                               const unsigned short* __restrict__ resp,
                                               float* __restrict__ out) {
    __shared__ float4 cf[8];
    int bid = blockIdx.x, tid = threadIdx.x;
    int base_row = (bid * 1024) / 400;
    if (tid < 8) {
        int row = base_row + tid;
        if (row < 4096) {
            int oc = row & 255;
            const float inv = 1.f / NTV;
            float s1 = stats[oc],       s2 = stats[256 + oc];
            float r1v = stats[512 + oc], r2v = stats[768 + oc];
            float mm = s1*inv, vm = s2*inv - mm*mm;
            float mr = r1v*inv, vr = r2v*inv - mr*mr;
            float a1 = bn_g[oc]  * rsqrtf(vm + 1e-5f);
            float c1 = bn_b[oc]  - a1*mm;
            float a2 = rbn_g[oc] * rsqrtf(vr + 1e-5f);
            float c2 = rbn_b[oc] - a2*mr;
            cf[tid] = make_float4(a1, c1, a2, c2);
        }
    }
    __syncthreads();

    const uint4* m4 = (const uint4*)mainp;
    const uint4* r4 = (const uint4*)resp;
    float4* o4 = (float4*)out;
#pragma unroll
    for (int r = 0; r < 4; r++) {
        int chunk = bid*1024 + r*256 + tid;
        uint4 mu = m4[chunk];
        uint4 ru = r4[chunk];
        float4 C = cf[chunk/400 - base_row];
        float4 f0, f1;
        f0.x = fmaxf(fmaf(C.x, __uint_as_float(mu.x << 16),        C.y)
                   + fmaf(C.z, __uint_as_float(ru.x << 16),        C.w), 0.f);
        f0.y = fmaxf(fmaf(C.x, __uint_as_float(mu.x & 0xffff0000u), C.y)
                   + fmaf(C.z, __uint_as_float(ru.x & 0xffff0000u), C.w), 0.f);
        f0.z = fmaxf(fmaf(C.x, __uint_as_float(mu.y << 16),        C.y)
                   + fmaf(C.z, __uint_as_float(ru.y << 16),        C.w), 0.f);
        f0.w = fmaxf(fmaf(C.x, __uint_as_float(mu.y & 0xffff0000u), C.y)
                   + fmaf(C.z, __uint_as_float(ru.y & 0xffff0000u), C.w), 0.f);
        f1.x = fmaxf(fmaf(C.x, __uint_as_float(mu.z << 16),        C.y)
                   + fmaf(C.z, __uint_as_float(ru.z << 16),        C.w), 0.f);
        f1.y = fmaxf(fmaf(C.x, __uint_as_float(mu.z & 0xffff0000u), C.y)
                   + fmaf(C.z, __uint_as_float(ru.z & 0xffff0000u), C.w), 0.f);
        f1.z = fmaxf(fmaf(C.x, __uint_as_float(mu.w << 16),        C.y)
                   + fmaf(C.z, __uint_as_float(ru.w << 16),        C.w), 0.f);
        f1.w = fmaxf(fmaf(C.x, __uint_as_float(mu.w & 0xffff0000u), C.y)
                   + fmaf(C.z, __uint_as_float(ru.w & 0xffff0000u), C.w), 0.f);
        o4[chunk*2]     = f0;
        o4[chunk*2 + 1] = f1;
    }
}

extern "C" void kernel_launch(void* const* d_in, const int* in_sizes, int n_in,
                              void* d_out, int out_size, void* d_ws, size_t ws_size,
                              hipStream_t stream) {
    const float* x        = (const float*)d_in[0];
    const int*   hop      = (const int*)  d_in[1];
    const float* emb      = (const float*)d_in[2];
    const float* A        = (const float*)d_in[3];
    const float* w_block  = (const float*)d_in[4];
    // d_in[5] b_block, d_in[9] res_b: per-channel biases cancel under batchnorm.
    const float* bn_g     = (const float*)d_in[6];
    const float* bn_b     = (const float*)d_in[7];
    const float* res_w    = (const float*)d_in[8];
    const float* rbn_g    = (const float*)d_in[10];
    const float* rbn_b    = (const float*)d_in[11];
    float* out = (float*)d_out;

    char* ws = (char*)d_ws;
    float*          stats  = (float*)(ws + B_STATS);
    unsigned short* E2     = (unsigned short*)(ws + B_E2);
    unsigned short* xb     = (unsigned short*)(ws + B_XB);
    unsigned short* mainp  = (unsigned short*)(ws + B_MAIN);
    unsigned short* resp   = (unsigned short*)(ws + B_RES);

    hipMemsetAsync(stats, 0, 4096, stream);   // capture-safe (harness reset uses it)
    k_prep2x <<<2976, 256, 0, stream>>>(hop, emb, A, res_w, w_block, E2, x, xb, resp, stats);
    k_gc     <<<1024, 256, 0, stream>>>(xb, E2, mainp, stats);
    k_final  <<<1600, 256, 0, stream>>>(bn_g, bn_b, rbn_g, rbn_b, stats, mainp, resp, out);
}

// Round 11
// 198.587 us; speedup vs baseline: 1.4413x; 1.0397x over previous
//
#include <hip/hip_runtime.h>
#include <stdint.h>

typedef __attribute__((ext_vector_type(8))) short short8;
typedef __attribute__((ext_vector_type(4))) float f32x4;

// ---- byte offsets into d_ws (total 74,054,656 B; proven ws >= 75.7 MB) ----
#define B_STATS  60416ull      // 4*256 fp32             = 4096
#define B_E2     1178624ull    // 8*8*13*128*32 bf16     = 6815744
#define B_XB     7994368ull    // 2048*3328 bf16         = 13631488
#define B_MAIN   21625856ull   // 16*256*128*25 bf16     = 26214400  (layout = out)
#define B_RES    47840256ull   // 16*256*128*25 bf16     = 26214400  (end 74054656)

#define NTV 51200.0f

__device__ __forceinline__ unsigned short f2bf(float f) {
    unsigned u = __float_as_uint(f);
    return (unsigned short)((u + 0x7fffu + ((u >> 16) & 1u)) >> 16);
}
__device__ __forceinline__ float bf2f(unsigned s) { return __uint_as_float(s << 16); }

__device__ __forceinline__ float wave_sum(float v) {
#pragma unroll
    for (int m = 1; m < 64; m <<= 1) v += __shfl_xor(v, m, 64);
    return v;
}

// async global->LDS, 16B per lane; HW dest = wave-uniform base + lane*16
__device__ __forceinline__ void gl_lds16(const unsigned short* g, unsigned short* l) {
    __builtin_amdgcn_global_load_lds(
        (const __attribute__((address_space(1))) unsigned int*)g,
        (__attribute__((address_space(3))) unsigned int*)l, 16, 0, 0);
}
__device__ __forceinline__ void stage_pair(const unsigned short* g0, const unsigned short* g1,
                                           unsigned short* d) {
    gl_lds16(g0, d);
    gl_lds16(g1, d + 512);
}

// LDS tile swizzle: data (row, quad) stored at short-idx (row^((row>>2)&1))*32 + ((quad^(row&3))<<3)
__device__ __forceinline__ int swz_idx(int row, int quad) {
    int rowX = row ^ ((row >> 2) & 1);
    return rowX * 32 + ((quad ^ (row & 3)) << 3);
}

// K-PREP2X: 3 independent jobs in one launch.
// bids [0,128):   E2 build with inline BnA.
// bids [128,928): residual GEMM; K-loop/stats = R8-exact. C-store now routed
//                 through a per-wave LDS transpose patch -> resp written as FULL
//                 64B lines (was: 64 scattered 2B stores/instr = TA serialization
//                 + RMW fetch; R8/R10's prep2x idle-pipe cost).
// bids [928,2976): x -> xb repack (R10: contiguous read, scatter write).
__global__ __launch_bounds__(256) void k_prep2x(const int* __restrict__ hop,
                                                const float* __restrict__ emb,
                                                const float* __restrict__ A,
                                                const float* __restrict__ res_w,
                                                const float* __restrict__ w_block,
                                                unsigned short* __restrict__ E2,
                                                const float* __restrict__ x,
                                                unsigned short* __restrict__ xb,
                                                unsigned short* __restrict__ resp,
                                                float* __restrict__ stats) {
    __shared__ __align__(16) char smem[16384];
    int bid = blockIdx.x, tid = threadIdx.x;

    if (bid < 128) {
        // ---- E2 build (inline BnA) ----
        float* bl = (float*)smem;            // 3*625 = 7500 B
        float* wl = (float*)smem + 1875;     // 3*64  =  768 B
        int half = bid & 1, og = (bid >> 1) & 7, h = bid >> 4;

        if (tid < 75) {                      // k3 = tid/25, w = tid%25
            int k3 = tid / 25, w = tid - k3*25;
            int g = k3*8 + h;
            float nb = 0.f, na = 0.f;
            for (int v = 0; v < 25; v++) {
                float e = emb[g*12 + hop[v*25 + w]];
                nb += e*e;
                float a = A[((size_t)g*25 + v)*25 + w];
                na += a*a;
            }
            nb = sqrtf(nb) + 1e-4f;
            na = sqrtf(na) + 1e-4f;
            for (int v = 0; v < 25; v++) {
                float e = emb[g*12 + hop[v*25 + w]];
                float a = A[((size_t)g*25 + v)*25 + w];
                bl[k3*625 + v*25 + w] = e/nb + a/na;
            }
        }
        if (tid < 192) {
            int k3 = tid >> 6, o = (tid >> 4) & 3, c = tid & 15;
            wl[tid] = w_block[(k3*256 + h*32 + og*4 + o)*16 + c];
        }
        __syncthreads();

        unsigned short* dst = E2 + (size_t)(h*8 + og)*53248;
        int e0 = half * 26624;
        for (int e = e0 + tid; e < e0 + 26624; e += 256) {
            int kc = e >> 12;
            int n  = (e >> 5) & 127;
            int kk = e & 31;
            int k  = kc*32 + kk;
            int o  = n >> 5, w = n & 31;
            float val = 0.f;
            if (k < 400 && w < 25) {
                int c = k / 25, v = k - c*25;
                val = wl[0*64 + o*16 + c] * bl[0*625 + v*25 + w]
                    + wl[1*64 + o*16 + c] * bl[1*625 + v*25 + w]
                    + wl[2*64 + o*16 + c] * bl[2*625 + v*25 + w];
            }
            dst[e] = f2bf(val);
        }
    } else if (bid < 928) {
        // ---- residual GEMM: M=(b,v)=51200 x K=128 x N=256 ----
        // pair (mt, nt=0/1) at bids b2, b2+400 -> same XCD (128%8==400%8==0)
        unsigned short* lds = (unsigned short*)smem;   // [A 4096][B 4096] shorts
        int b2 = bid - 128;
        int nt = (b2 >= 400) ? 1 : 0;
        int mt = b2 - nt*400;

        int lane = tid & 63, wave = tid >> 6;
        int wm = wave >> 1, wn = wave & 1;
        int lane15 = lane & 15, quad = lane >> 4;

        int n  = mt / 25;
        int off = (mt - n*25) * 128;
        const float* xb2 = x + (size_t)n*409600 + off;
        const float* rw  = res_w + (size_t)nt*128*128;   // [128 rows][128 cols]

        int c2 = tid >> 4, seg = tid & 15;   // c-pair (2c2,2c2+1), m = seg + 16j
        int wbase = 2*(c2 & 3), qn = c2 >> 2;

        f32x4 acc[4][4] = {};

        for (int kc = 0; kc < 4; kc++) {
            const float* xc0 = xb2 + (size_t)(kc*32 + 2*c2)*3200;
            const float* xc1 = xc0 + 3200;
            const float2* rp2 = (const float2*)(rw + kc*32 + 2*c2);  // row stride 64 float2
#pragma unroll
            for (int j = 0; j < 8; j++) {
                int m = seg + 16*j;
                unsigned pkA = (unsigned)f2bf(xc0[m]) | ((unsigned)f2bf(xc1[m]) << 16);
                *(unsigned*)&lds[swz_idx(m, qn) + wbase] = pkA;
                float2 rv = rp2[m*64];
                unsigned pkB = (unsigned)f2bf(rv.x) | ((unsigned)f2bf(rv.y) << 16);
                *(unsigned*)&lds[4096 + swz_idx(m, qn) + wbase] = pkB;
            }
            __syncthreads();

            short8 af[4], bq[4];
#pragma unroll
            for (int i = 0; i < 4; i++) {
                af[i] = *(const short8*)&lds[swz_idx(wm*64 + i*16 + lane15, quad)];
                bq[i] = *(const short8*)&lds[4096 + swz_idx(wn*64 + i*16 + lane15, quad)];
            }
#pragma unroll
            for (int i = 0; i < 4; i++)
#pragma unroll
                for (int j = 0; j < 4; j++)
                    acc[i][j] = __builtin_amdgcn_mfma_f32_16x16x32_bf16(af[i], bq[j], acc[i][j], 0, 0, 0);
            __syncthreads();
        }

        // ---- C-store via per-wave LDS transpose patch (tiles are dead; 4x4KB) ----
        // patch layout [ocl 64][m2l 32] bf16, granule(4-short)-swizzled:
        //   (ocl, m2l) at short-idx ocl*32 + (m2l ^ ((ocl&7)<<2)).
        unsigned short* patch = lds + wave*2048;
        const size_t rbase = (size_t)n*819200 + (size_t)(nt*128 + wn*64)*3200
                           + off + wm*64;
        int o8 = lane >> 3, g = lane & 7;
#pragma unroll
        for (int p = 0; p < 2; p++) {
#pragma unroll
            for (int ii = 0; ii < 2; ii++) {
                int i = p*2 + ii;
                int m2l = ii*16 + quad*4;
#pragma unroll
                for (int j = 0; j < 4; j++) {
                    int ocl = j*16 + lane15;
                    unsigned lo = (unsigned)f2bf(acc[i][j][0]) | ((unsigned)f2bf(acc[i][j][1]) << 16);
                    unsigned hi = (unsigned)f2bf(acc[i][j][2]) | ((unsigned)f2bf(acc[i][j][3]) << 16);
                    *(uint2*)&patch[ocl*32 + (m2l ^ ((ocl & 7) << 2))] = make_uint2(lo, hi);
                }
            }
            asm volatile("s_waitcnt lgkmcnt(0)" ::: "memory");   // wave-local: writes done
#pragma unroll
            for (int ro = 0; ro < 8; ro++) {
                int ocl = ro*8 + o8;
                uint2 v = *(const uint2*)&patch[ocl*32 + ((g*4) ^ (o8 << 2))];
                *(uint2*)(resp + rbase + (size_t)ocl*3200 + p*32 + g*4) = v;
            }
            asm volatile("" ::: "memory");   // keep pass-1 LDS writes after pass-0 reads
        }

        // ---- stats (values & add order identical to R8) ----
#pragma unroll
        for (int j = 0; j < 4; j++) {
            int oc = nt*128 + wn*64 + j*16 + lane15;
            float s1 = 0.f, s2 = 0.f;
#pragma unroll
            for (int i = 0; i < 4; i++)
#pragma unroll
                for (int r = 0; r < 4; r++) {
                    float val = acc[i][j][r];
                    s1 += val;
                    s2 = fmaf(val, val, s2);
                }
            s1 += __shfl_xor(s1, 16, 64); s1 += __shfl_xor(s1, 32, 64);
            s2 += __shfl_xor(s2, 16, 64); s2 += __shfl_xor(s2, 32, 64);
            if (quad == 0) {
                atomicAdd(&stats[512 + oc], s1);
                atomicAdd(&stats[768 + oc], s2);
            }
        }
    } else {
        // ---- x -> xb repack, block = (n,c): contiguous read, scatter write ----
        int b = bid - 928;                   // b = n*128 + c
        int n_ = b >> 7, c = b & 127;
        const float* src = x + (size_t)b * 3200;
        unsigned short* dstBase = xb + (size_t)n_*128*3328 + (c >> 4)*416 + (c & 15)*25;
        for (int idx = tid; idx < 3200; idx += 256) {
            int t = idx / 25, v = idx - t*25;
            dstBase[(size_t)t*3328 + v] = f2bf(src[idx]);
        }
        if (c < 8) {                         // zero pads kb=c for all t of this n
            unsigned short* p = xb + (size_t)n_*128*3328 + c*416 + 400;
            int t = tid >> 1, j = (tid & 1) * 8;
            *(uint4*)&p[(size_t)t*3328 + j] = make_uint4(0, 0, 0, 0);
        }
    }
}

// K-GC: pure main GEMM, 1024 blocks, R2-exact loop. 2x16KB dbuf,
// stage-next-before-compute, ONE syncthreads per iter. XCD-pinned h=bid&7.
// Output layout [n][oc][t][v] (= out).
__global__ __launch_bounds__(256) void k_gc(const unsigned short* __restrict__ xb,
                                            const unsigned short* __restrict__ E2,
                                            unsigned short* __restrict__ mainp,
                                            float* __restrict__ stats) {
    __shared__ unsigned short lds[16384];
    int bid = blockIdx.x, tid = threadIdx.x;
    int lane = tid & 63, wave = tid >> 6;
    int wm = wave >> 1, wn = wave & 1;
    int lane15 = lane & 15, quad = lane >> 4;

    // inverse swizzle for linear gl_lds destinations (loop-invariant)
    int Lrow0 = wave*32 + (lane >> 2), Lq = lane & 3;
    int r0 = Lrow0 ^ ((Lrow0 >> 2) & 1), q0 = Lq ^ (r0 & 3);
    int Lrow1 = Lrow0 + 16;
    int r1 = Lrow1 ^ ((Lrow1 >> 2) & 1), q1 = Lq ^ (r1 & 3);
    const int adoff = wave*1024 + lane*8;

    int h = bid & 7, og = (bid >> 3) & 7, mt = bid >> 6;

    const unsigned short* agA0 = xb + (size_t)(mt*128 + r0)*3328 + h*416 + q0*8;
    const unsigned short* agA1 = xb + (size_t)(mt*128 + r1)*3328 + h*416 + q1*8;
    const unsigned short* eb   = E2 + (size_t)(h*8 + og)*53248;
    const unsigned short* bgB0 = eb + r0*32 + q0*8;
    const unsigned short* bgB1 = eb + r1*32 + q1*8;

    f32x4 acc[4][4] = {};

    // prologue: stage kc=0 into buf0
    stage_pair(agA0, agA1, lds + adoff);
    stage_pair(bgB0, bgB1, lds + 4096 + adoff);
    __syncthreads();

    for (int kc = 0; kc < 13; kc++) {
        int cur = (kc & 1) << 13;            // 0 or 8192
        if (kc < 12) {
            int nxt = 8192 - cur;
            stage_pair(agA0 + (kc+1)*32,           agA1 + (kc+1)*32,           lds + nxt + adoff);
            stage_pair(bgB0 + (size_t)(kc+1)*4096, bgB1 + (size_t)(kc+1)*4096, lds + nxt + 4096 + adoff);
            __builtin_amdgcn_sched_barrier(0);   // keep stage issue ahead of compute
        }
        const unsigned short* Ac = lds + cur;
        const unsigned short* Bc = lds + cur + 4096;

        short8 af[4], bq[4];
#pragma unroll
        for (int i = 0; i < 4; i++) {
            af[i] = *(const short8*)&Ac[swz_idx(wm*64 + i*16 + lane15, quad)];
            bq[i] = *(const short8*)&Bc[swz_idx(wn*64 + i*16 + lane15, quad)];
        }
#pragma unroll
        for (int i = 0; i < 4; i++)
#pragma unroll
            for (int j = 0; j < 4; j++)
                acc[i][j] = __builtin_amdgcn_mfma_f32_16x16x32_bf16(af[i], bq[j], acc[i][j], 0, 0, 0);
        if (kc < 12) __syncthreads();        // drains this iter's stage (post-MFMA: cheap)
    }

    // epilogue: n = wn*64 + j*16 + lane15 = o*32 + w; mainp layout [n][oc][t][w]
    float s1[2] = {0.f, 0.f}, s2[2] = {0.f, 0.f};
#pragma unroll
    for (int j = 0; j < 4; j++) {
        int w = (j & 1)*16 + lane15;
        int p = j >> 1;
        if (w < 25) {
            int oc = h*32 + og*4 + wn*2 + p;
#pragma unroll
            for (int i = 0; i < 4; i++) {
                int tb = wm*64 + i*16 + quad*4;
#pragma unroll
                for (int r = 0; r < 4; r++) {
                    float val = acc[i][j][r];
                    mainp[((size_t)(mt*256 + oc)*128 + tb + r)*25 + w] = f2bf(val);
                    s1[p] += val;
                    s2[p] = fmaf(val, val, s2[p]);
                }
            }
        }
    }
#pragma unroll
    for (int p = 0; p < 2; p++) {
        float a = wave_sum(s1[p]);
        float b = wave_sum(s2[p]);
        if (lane == 0) {
            int oc = h*32 + og*4 + wn*2 + p;
            atomicAdd(&stats[oc], a);
            atomicAdd(&stats[256 + oc], b);
        }
    }
}

// K-FINAL: out = relu(BN1(main) + BN2(res)); mainp/resp layout == out layout ->
// pure coalesced affine elementwise. 1600 blocks x 256 thr x 4 chunks x 8 elems.
__global__ __launch_bounds__(256) void k_final(const float* __restrict__ bn_g,
                                               const float* __restrict__ bn_b,
                                               const float* __restrict__ rbn_g,
                                               const float* __restrict__ rbn_b,
                                               const float* __restrict__ stats,
                                               const unsigned short* __restrict__ mainp,
                                               const unsigned short* __restrict__ resp,
                                               float* __restrict__ out) {
    __shared__ float4 cf[8];
    int bid = blockIdx.x, tid = threadIdx.x;
    int base_row = (bid * 1024) / 400;
    if (tid < 8) {
        int row = base_row + tid;
        if (row < 4096) {
            int oc = row & 255;
            const float inv = 1.f / NTV;
            float s1 = stats[oc],       s2 = stats[256 + oc];
            float r1v = stats[512 + oc], r2v = stats[768 + oc];
            float mm = s1*inv, vm = s2*inv - mm*mm;
            float mr = r1v*inv, vr = r2v*inv - mr*mr;
            float a1 = bn_g[oc]  * rsqrtf(vm + 1e-5f);
            float c1 = bn_b[oc]  - a1*mm;
            float a2 = rbn_g[oc] * rsqrtf(vr + 1e-5f);
            float c2 = rbn_b[oc] - a2*mr;
            cf[tid] = make_float4(a1, c1, a2, c2);
        }
    }
    __syncthreads();

    const uint4* m4 = (const uint4*)mainp;
    const uint4* r4 = (const uint4*)resp;
    float4* o4 = (float4*)out;
#pragma unroll
    for (int r = 0; r < 4; r++) {
        int chunk = bid*1024 + r*256 + tid;
        uint4 mu = m4[chunk];
        uint4 ru = r4[chunk];
        float4 C = cf[chunk/400 - base_row];
        float4 f0, f1;
        f0.x = fmaxf(fmaf(C.x, __uint_as_float(mu.x << 16),        C.y)
                   + fmaf(C.z, __uint_as_float(ru.x << 16),        C.w), 0.f);
        f0.y = fmaxf(fmaf(C.x, __uint_as_float(mu.x & 0xffff0000u), C.y)
                   + fmaf(C.z, __uint_as_float(ru.x & 0xffff0000u), C.w), 0.f);
        f0.z = fmaxf(fmaf(C.x, __uint_as_float(mu.y << 16),        C.y)
                   + fmaf(C.z, __uint_as_float(ru.y << 16),        C.w), 0.f);
        f0.w = fmaxf(fmaf(C.x, __uint_as_float(mu.y & 0xffff0000u), C.y)
                   + fmaf(C.z, __uint_as_float(ru.y & 0xffff0000u), C.w), 0.f);
        f1.x = fmaxf(fmaf(C.x, __uint_as_float(mu.z << 16),        C.y)
                   + fmaf(C.z, __uint_as_float(ru.z << 16),        C.w), 0.f);
        f1.y = fmaxf(fmaf(C.x, __uint_as_float(mu.z & 0xffff0000u), C.y)
                   + fmaf(C.z, __uint_as_float(ru.z & 0xffff0000u), C.w), 0.f);
        f1.z = fmaxf(fmaf(C.x, __uint_as_float(mu.w << 16),        C.y)
                   + fmaf(C.z, __uint_as_float(ru.w << 16),        C.w), 0.f);
        f1.w = fmaxf(fmaf(C.x, __uint_as_float(mu.w & 0xffff0000u), C.y)
                   + fmaf(C.z, __uint_as_float(ru.w & 0xffff0000u), C.w), 0.f);
        o4[chunk*2]     = f0;
        o4[chunk*2 + 1] = f1;
    }
}

extern "C" void kernel_launch(void* const* d_in, const int* in_sizes, int n_in,
                              void* d_out, int out_size, void* d_ws, size_t ws_size,
                              hipStream_t stream) {
    const float* x        = (const float*)d_in[0];
    const int*   hop      = (const int*)  d_in[1];
    const float* emb      = (const float*)d_in[2];
    const float* A        = (const float*)d_in[3];
    const float* w_block  = (const float*)d_in[4];
    // d_in[5] b_block, d_in[9] res_b: per-channel biases cancel under batchnorm.
    const float* bn_g     = (const float*)d_in[6];
    const float* bn_b     = (const float*)d_in[7];
    const float* res_w    = (const float*)d_in[8];
    const float* rbn_g    = (const float*)d_in[10];
    const float* rbn_b    = (const float*)d_in[11];
    float* out = (float*)d_out;

    char* ws = (char*)d_ws;
    float*          stats  = (float*)(ws + B_STATS);
    unsigned short* E2     = (unsigned short*)(ws + B_E2);
    unsigned short* xb     = (unsigned short*)(ws + B_XB);
    unsigned short* mainp  = (unsigned short*)(ws + B_MAIN);
    unsigned short* resp   = (unsigned short*)(ws + B_RES);

    hipMemsetAsync(stats, 0, 4096, stream);   // capture-safe (harness reset uses it)
    k_prep2x <<<2976, 256, 0, stream>>>(hop, emb, A, res_w, w_block, E2, x, xb, resp, stats);
    k_gc     <<<1024, 256, 0, stream>>>(xb, E2, mainp, stats);
    k_final  <<<1600, 256, 0, stream>>>(bn_g, bn_b, rbn_g, rbn_b, stats, mainp, resp, out);
}